// Round 1
// baseline (426.424 us; speedup 1.0000x reference)
//
#include <hip/hip_runtime.h>

#define FWHT_N 4096
#define TPB 256
#define LDS_WORDS 4096
#define MAX_BLOCKS 2048   // 256 CUs x 8 blocks; 16384 rows -> 8 rows/block

// FWHT over 16 register-resident values, distances 1,2,4,8 (Sylvester order).
// Register bit m_b maps to a global index bit; butterfly stages over disjoint
// bits commute, so splitting the 12 bits into three groups of 4 (any order)
// reproduces H = H2^{(x)12} exactly.
__device__ __forceinline__ void fwht16(float a[16]) {
#pragma unroll
    for (int h = 1; h < 16; h <<= 1) {
#pragma unroll
        for (int i = 0; i < 16; i += 2 * h) {
#pragma unroll
            for (int j = i; j < i + h; ++j) {
                float u = a[j];
                float v = a[j + h];
                a[j]     = u + v;
                a[j + h] = u - v;
            }
        }
    }
}

// LDS address map: A(i) = i ^ (((i>>6)&15) << 2).
// BIJECTIVE: the XOR only flips bits 2..5, which don't feed i>>6, so
// i = A ^ (((A>>6)&15)<<2).
// Bank analysis (32 banks, per wave):
//  - exchange-1 b128 writes: quad starts uniform over the 8 slots mod 32
//    -> 8 words/bank = structural floor for 256 words -> conflict-free
//  - pass-B b32 r/w: bank = (t&3) + 4*((m&7)^((t>>2)&7)) -> exactly 2-way, free
//  - pass-C b32 reads: bank = (l&31) ^ ((m&7)<<2) -> exactly 2-way, free

__global__ __launch_bounds__(TPB, 4) void fwht_rows_kernel(
        const float* __restrict__ x,
        const float* __restrict__ s,
        float* __restrict__ out,
        const int rows) {
    __shared__ float lds[LDS_WORDS];

    const int t = threadIdx.x;
    const float scale = 0.015625f;  // 1/sqrt(4096)

    // ---- s hoisted into registers ONCE per persistent block (was: re-read
    // from global by every one of 16384 blocks). Same index map as pass A.
    float sv[16];
#pragma unroll
    for (int k = 0; k < 4; ++k) {
        float4 ss = *(const float4*)(s + 4 * t + 1024 * k);
        sv[4 * k + 0] = ss.x;
        sv[4 * k + 1] = ss.y;
        sv[4 * k + 2] = ss.z;
        sv[4 * k + 3] = ss.w;
    }

    const int stride = gridDim.x;
    int row = blockIdx.x;

    // ---- Software pipeline: xn[] always holds the NEXT row to be processed.
    float xn[16];
    if (row < rows) {
        const float* xr = x + (size_t)row * FWHT_N;
#pragma unroll
        for (int k = 0; k < 4; ++k) {
            float4 xx = *(const float4*)(xr + 4 * t + 1024 * k);
            xn[4 * k + 0] = xx.x;
            xn[4 * k + 1] = xx.y;
            xn[4 * k + 2] = xx.z;
            xn[4 * k + 3] = xx.w;
        }
    }

    for (; row < rows; row += stride) {
        // Consume the staged row, then immediately issue the next row's loads
        // so their ~900-cycle HBM latency hides under this row's three FWHT
        // passes + LDS exchanges + store.
        float a[16];
#pragma unroll
        for (int m = 0; m < 16; ++m) a[m] = xn[m] * sv[m];

        const int nrow = row + stride;
        if (nrow < rows) {
            const float* xr = x + (size_t)nrow * FWHT_N;
#pragma unroll
            for (int k = 0; k < 4; ++k) {
                float4 xx = *(const float4*)(xr + 4 * t + 1024 * k);
                xn[4 * k + 0] = xx.x;
                xn[4 * k + 1] = xx.y;
                xn[4 * k + 2] = xx.z;
                xn[4 * k + 3] = xx.w;
            }
        }

        // ---- Pass A: idx bits {0,1,10,11}. Thread t owns idx = 4t + j + 1024k.
        fwht16(a);

        // ---- Exchange 1: four ds_write_b128. j in 0..3 only touches bits 0..1,
        // the XOR only bits 2..5, so A(i+j) = A(i)+j -> quads stay contiguous.
#pragma unroll
        for (int k = 0; k < 4; ++k) {
            int i    = 4 * t + 1024 * k;
            int addr = i ^ (((i >> 6) & 15) << 2);
            *(float4*)(lds + addr) =
                make_float4(a[4 * k + 0], a[4 * k + 1], a[4 * k + 2], a[4 * k + 3]);
        }
        __syncthreads();

        // ---- Pass B: idx bits {2..5}. Thread owns idx = (t&3) + 4m + 64*(t>>2).
        // idx>>6 = t>>2, so A(idx) = 64*(t>>2) + (t&3) + 4*(m ^ ((t>>2)&15)).
        {
            const int w    = t >> 2;
            const int base = 64 * w + (t & 3);
            const int swz  = w & 15;
#pragma unroll
            for (int m = 0; m < 16; ++m) a[m] = lds[base + 4 * (m ^ swz)];
            fwht16(a);
            // Same cells, same thread: no barrier between this read and write.
#pragma unroll
            for (int m = 0; m < 16; ++m) lds[base + 4 * (m ^ swz)] = a[m];
        }
        __syncthreads();

        // ---- Pass C: idx bits {6..9}. Thread owns idx = (t&63) + 64m + 1024*(t>>6).
        // (idx>>6)&15 = m, so A(idx) = 1024*(t>>6) + 64m + ((t&63) ^ (m<<2)).
        {
            const int hi = 1024 * (t >> 6);
            const int lo = t & 63;
#pragma unroll
            for (int m = 0; m < 16; ++m) a[m] = lds[hi + 64 * m + (lo ^ (m << 2))];
        }
        fwht16(a);

        // ---- Scale and store: out[(t&63) + 64m + 1024*(t>>6)].
        // Per instruction: 256 B contiguous per wave; full lines across the block.
        {
            float* orw = out + (size_t)row * FWHT_N;
            const int baseO = (t & 63) + 1024 * (t >> 6);
#pragma unroll
            for (int m = 0; m < 16; ++m) {
                orw[baseO + 64 * m] = a[m] * scale;
            }
        }

        // Protect LDS: next iteration's exchange-1 writes must not race this
        // iteration's pass-C reads from other waves.
        __syncthreads();
    }
}

extern "C" void kernel_launch(void* const* d_in, const int* in_sizes, int n_in,
                              void* d_out, int out_size, void* d_ws, size_t ws_size,
                              hipStream_t stream) {
    const float* x = (const float*)d_in[0];
    const float* s = (const float*)d_in[1];
    float* out = (float*)d_out;
    const int rows = in_sizes[0] / FWHT_N;  // 16384
    const int blocks = rows < MAX_BLOCKS ? rows : MAX_BLOCKS;
    fwht_rows_kernel<<<blocks, TPB, 0, stream>>>(x, s, out, rows);
}